// Round 8
// baseline (59.850 us; speedup 1.0000x reference)
//
#include <hip/hip_runtime.h>
#include <math.h>

constexpr int NUM_HEADS    = 32;
constexpr int NUM_KV_HEADS = 8;
constexpr int HEAD_DIM     = 128;
constexpr int BS           = 16;
constexpr int KV_LEN       = 2048;
constexpr int GROUP        = NUM_HEADS / NUM_KV_HEADS; // 4
constexpr int NCHUNK       = 32;
constexpr int CHUNK        = KV_LEN / NCHUNK;          // 64 positions/block
constexpr int TPOS         = 4;                        // positions per tile
constexpr int NT           = CHUNK / TPOS;             // 16 tiles
constexpr int ROWF         = NUM_KV_HEADS * HEAD_DIM;  // 1024 floats per slot row
constexpr int POSSTRIDE    = 2 * ROWF + 8;             // K|V|pad, 2056 floats (+8 breaks bank aliasing)

// async 16B/lane -> LDS (wave covers 1KB contiguous). LDS dest = uniform base + lane*16.
__device__ __forceinline__ void dma16(const float* g, float* l) {
    __builtin_amdgcn_global_load_lds(
        (const __attribute__((address_space(1))) void*)g,
        (__attribute__((address_space(3))) void*)l, 16, 0, 0);
}

// One block per (b, chunk): 512 blocks x 512 threads (8 waves = 8 kv-heads).
// Staging fetches FULL 4KB slot rows (all heads at once) -> sequential DRAM
// bursts instead of 8 independent random 512B reads (R0-R6's shared flaw).
// Wave w stages quarter (w&3) of array (w>>2) for each of the tile's 4 slots;
// compute: wave w = kv-head w, 16-lane-per-position groups as in R4/R6.
__global__ __launch_bounds__(512, 2) void attn_partial_kernel(
    const float* __restrict__ q,
    const float* __restrict__ knew,
    const float* __restrict__ vnew,
    const float* __restrict__ k_cache,
    const float* __restrict__ v_cache,
    const int*   __restrict__ page_indices,
    float* __restrict__ ws_o,
    float* __restrict__ ws_m,
    float* __restrict__ ws_s)
{
    const int bid   = blockIdx.x;
    const int chunk = bid % NCHUNK;
    const int b     = bid / NCHUNK;

    const int tid  = threadIdx.x;
    const int wid  = tid >> 6;    // 0..7 = kv-head for compute
    const int lane = tid & 63;
    const int g    = lane >> 4;   // position slot within tile (0..3)
    const int sub  = lane & 15;   // dim slice
    const int h    = wid;
    const int arr  = wid >> 2;    // staging role: 0=K, 1=V
    const int quar = wid & 3;     // staging role: row quarter (1KB)

    const int lbase = chunk * CHUNK;

    __shared__ float smem[2][TPOS][POSSTRIDE];   // 64.3 KB -> 2 blocks/CU

    // fold SCALE and log2(e) into q so softmax uses exp2f directly
    const float qscale = 0.08838834764831845f * 1.4426950408889634f;

    float qv[GROUP][8];
#pragma unroll
    for (int hg = 0; hg < GROUP; ++hg) {
        const float* qp = q + ((size_t)b * NUM_HEADS + h * GROUP + hg) * HEAD_DIM;
        const float4 a = *(const float4*)(qp + sub * 4);
        const float4 c = *(const float4*)(qp + 64 + sub * 4);
        qv[hg][0] = a.x * qscale; qv[hg][1] = a.y * qscale;
        qv[hg][2] = a.z * qscale; qv[hg][3] = a.w * qscale;
        qv[hg][4] = c.x * qscale; qv[hg][5] = c.y * qscale;
        qv[hg][6] = c.z * qscale; qv[hg][7] = c.w * qscale;
    }

    float m[GROUP], ssum[GROUP], o[GROUP][8];
#pragma unroll
    for (int hg = 0; hg < GROUP; ++hg) {
        m[hg] = -INFINITY; ssum[hg] = 0.f;
#pragma unroll
        for (int j = 0; j < 8; ++j) o[hg][j] = 0.f;
    }

    const float* kcnew = knew + (size_t)b * ROWF;   // fresh token rows (all heads)
    const float* vcnew = vnew + (size_t)b * ROWF;

    // stage tile t's 4 slot rows; idx[] are block-uniform (scalar regs)
    auto stage = [&](int buf, int t, const int idx[TPOS]) {
#pragma unroll
        for (int j = 0; j < TPOS; ++j) {
            const int l = lbase + t * TPOS + j;
            const float* src;
            if (l == KV_LEN - 1)   // freshly written token (permutation => only hit)
                src = arr ? vcnew : kcnew;
            else
                src = (arr ? v_cache : k_cache) + (size_t)idx[j] * ROWF;
            dma16(src + quar * 256 + lane * 4,
                  &smem[buf][j][arr * ROWF + quar * 256]);
        }
    };

    int nidx[TPOS];
#pragma unroll
    for (int j = 0; j < TPOS; ++j) nidx[j] = page_indices[b * KV_LEN + lbase + j];
    stage(0, 0, nidx);
#pragma unroll
    for (int j = 0; j < TPOS; ++j) nidx[j] = page_indices[b * KV_LEN + lbase + TPOS + j];

#pragma unroll 1   // keep ROLLED (R1-R4: unroll -> scratch spill)
    for (int t = 0; t < NT; ++t) {
        __syncthreads();   // stage(t) landed; everyone done reading buf t&1^1

        if (t + 1 < NT) {
            stage((t + 1) & 1, t + 1, nidx);
            if (t + 2 < NT) {
#pragma unroll
                for (int j = 0; j < TPOS; ++j)
                    nidx[j] = page_indices[b * KV_LEN + lbase + (t + 2) * TPOS + j];
            }
        }

        // compute tile t: group g -> position g, head h = wid
        const float* bp = &smem[t & 1][g][0];
        const float4 k0 = *(const float4*)(bp + h * HEAD_DIM + sub * 4);
        const float4 k1 = *(const float4*)(bp + h * HEAD_DIM + 64 + sub * 4);
        const float4 v0 = *(const float4*)(bp + ROWF + h * HEAD_DIM + sub * 4);
        const float4 v1 = *(const float4*)(bp + ROWF + h * HEAD_DIM + 64 + sub * 4);

        float sc[GROUP];
#pragma unroll
        for (int hg = 0; hg < GROUP; ++hg) {
            sc[hg] = qv[hg][0] * k0.x + qv[hg][1] * k0.y + qv[hg][2] * k0.z + qv[hg][3] * k0.w
                   + qv[hg][4] * k1.x + qv[hg][5] * k1.y + qv[hg][6] * k1.z + qv[hg][7] * k1.w;
        }
#pragma unroll
        for (int off = 1; off < 16; off <<= 1) {
#pragma unroll
            for (int hg = 0; hg < GROUP; ++hg)
                sc[hg] += __shfl_xor(sc[hg], off, 64);
        }
#pragma unroll
        for (int hg = 0; hg < GROUP; ++hg) {
            const float mn = fmaxf(m[hg], sc[hg]);
            const float cf = exp2f(m[hg] - mn);
            const float pr = exp2f(sc[hg] - mn);
            ssum[hg] = ssum[hg] * cf + pr;
            m[hg] = mn;
            o[hg][0] = o[hg][0] * cf + pr * v0.x;
            o[hg][1] = o[hg][1] * cf + pr * v0.y;
            o[hg][2] = o[hg][2] * cf + pr * v0.z;
            o[hg][3] = o[hg][3] * cf + pr * v0.w;
            o[hg][4] = o[hg][4] * cf + pr * v1.x;
            o[hg][5] = o[hg][5] * cf + pr * v1.y;
            o[hg][6] = o[hg][6] * cf + pr * v1.z;
            o[hg][7] = o[hg][7] * cf + pr * v1.w;
        }
    }

    // combine the 4 position-groups within the wave (partner lanes share `sub`)
#pragma unroll
    for (int off = 16; off <= 32; off <<= 1) {
#pragma unroll
        for (int hg = 0; hg < GROUP; ++hg) {
            const float mo = __shfl_xor(m[hg], off, 64);
            const float so = __shfl_xor(ssum[hg], off, 64);
            float oo[8];
#pragma unroll
            for (int j = 0; j < 8; ++j) oo[j] = __shfl_xor(o[hg][j], off, 64);
            const float mn = fmaxf(m[hg], mo);
            const float c1 = exp2f(m[hg] - mn);
            const float c2 = exp2f(mo - mn);
            ssum[hg] = ssum[hg] * c1 + so * c2;
#pragma unroll
            for (int j = 0; j < 8; ++j) o[hg][j] = o[hg][j] * c1 + oo[j] * c2;
            m[hg] = mn;
        }
    }

    // each wave owns kv-head h outright: write partials directly, no cross-wave reduce
    if (lane < 16) {
        const size_t pb0 = (((size_t)chunk * BS + b) * NUM_KV_HEADS + h) * GROUP;
#pragma unroll
        for (int hg = 0; hg < GROUP; ++hg) {
            float* op = ws_o + (pb0 + hg) * HEAD_DIM;
            *(float4*)(op + sub * 4)      = make_float4(o[hg][0], o[hg][1], o[hg][2], o[hg][3]);
            *(float4*)(op + 64 + sub * 4) = make_float4(o[hg][4], o[hg][5], o[hg][6], o[hg][7]);
        }
        if (sub == 0) {
#pragma unroll
            for (int hg = 0; hg < GROUP; ++hg) { ws_m[pb0 + hg] = m[hg]; ws_s[pb0 + hg] = ssum[hg]; }
        }
    }
}

// Combine NCHUNK partials per (b, kv_head, group_head); one block per output head row.
__global__ __launch_bounds__(128) void attn_combine_kernel(
    const float* __restrict__ ws_o,
    const float* __restrict__ ws_m,
    const float* __restrict__ ws_s,
    float* __restrict__ out)
{
    const int bid = blockIdx.x;               // BS * NUM_KV_HEADS * GROUP = 512
    const int hg  = bid % GROUP;
    const int h   = (bid / GROUP) % NUM_KV_HEADS;
    const int b   = bid / (GROUP * NUM_KV_HEADS);
    const int d   = threadIdx.x;

    float mx = -INFINITY;
#pragma unroll 8
    for (int c = 0; c < NCHUNK; ++c) {
        const float mv = ws_m[(((size_t)c * BS + b) * NUM_KV_HEADS + h) * GROUP + hg];
        mx = fmaxf(mx, mv);
    }
    float stot = 0.f, acc = 0.f;
#pragma unroll 8
    for (int c = 0; c < NCHUNK; ++c) {
        const size_t pbase = (((size_t)c * BS + b) * NUM_KV_HEADS + h) * GROUP + hg;
        const float cf = exp2f(ws_m[pbase] - mx);
        stot += ws_s[pbase] * cf;
        acc  += ws_o[pbase * HEAD_DIM + d] * cf;
    }
    out[((size_t)b * NUM_HEADS + h * GROUP + hg) * HEAD_DIM + d] = acc / stot;
}

extern "C" void kernel_launch(void* const* d_in, const int* in_sizes, int n_in,
                              void* d_out, int out_size, void* d_ws, size_t ws_size,
                              hipStream_t stream)
{
    const float* q       = (const float*)d_in[0];
    const float* k       = (const float*)d_in[1];
    const float* v       = (const float*)d_in[2];
    const float* k_cache = (const float*)d_in[3];
    const float* v_cache = (const float*)d_in[4];
    // d_in[5] = slot_mapping (== page_indices[:, -1], handled via l == KV_LEN-1 rule)
    const int* page_indices = (const int*)d_in[6];
    float* out = (float*)d_out;

    float* ws_o = (float*)d_ws;   // NCHUNK*BS*8*4*128 floats = 8 MB
    float* ws_m = ws_o + (size_t)NCHUNK * BS * NUM_KV_HEADS * GROUP * HEAD_DIM;
    float* ws_s = ws_m + (size_t)NCHUNK * BS * NUM_KV_HEADS * GROUP;

    attn_partial_kernel<<<BS * NCHUNK, 512, 0, stream>>>(
        q, k, v, k_cache, v_cache, page_indices, ws_o, ws_m, ws_s);
    attn_combine_kernel<<<BS * NUM_KV_HEADS * GROUP, 128, 0, stream>>>(
        ws_o, ws_m, ws_s, out);
}